// Round 1
// baseline (811.927 us; speedup 1.0000x reference)
//
#include <hip/hip_runtime.h>
#include <math.h>

#define HID 150
#define EMB 300
#define NOUT 5
#define NNODES 8191
#define NLEAF 4096
#define LEAF_START 4095

constexpr int NBL = 16;   // leaves per block
constexpr int NBI = 8;    // internal nodes per block
constexpr int LOSS_BLOCKS = 32;

__device__ __forceinline__ float sigmoidf_(float x) { return 1.0f / (1.0f + __expf(-x)); }

// Build e-major (transposed) weight layouts so per-column weight loads are
// coalesced across lanes.
// Wt: [300][450]  cols: 0..149 Wi, 150..299 Wo, 300..449 Wu
// Ut: [300][750]  cols per gate g*150+h, gates: 0=i,1=fl,2=fr,3=o,4=u
//     rows e<150 from left-child matrices (U0*), e>=150 from right (U1*)
__global__ __launch_bounds__(256) void prep_kernel(
    const float* __restrict__ Wi, const float* __restrict__ Wo, const float* __restrict__ Wu,
    const float* __restrict__ U0i, const float* __restrict__ U1i,
    const float* __restrict__ U00f, const float* __restrict__ U01f,
    const float* __restrict__ U10f, const float* __restrict__ U11f,
    const float* __restrict__ U0o, const float* __restrict__ U1o,
    const float* __restrict__ U0u, const float* __restrict__ U1u,
    float* __restrict__ Wt, float* __restrict__ Ut)
{
    int idx = blockIdx.x * 256 + threadIdx.x;
    if (idx < EMB * 450) {
        int e = idx / 450, j = idx - e * 450;
        const float* W; int h;
        if (j < 150)      { W = Wi; h = j; }
        else if (j < 300) { W = Wo; h = j - 150; }
        else              { W = Wu; h = j - 300; }
        Wt[idx] = W[h * EMB + e];
    }
    if (idx < EMB * 750) {
        int e = idx / 750, j = idx - e * 750;
        int g = j / 150, h = j - g * 150;
        const float* U;
        if (e < 150) {
            U = (g == 0) ? U0i : (g == 1) ? U00f : (g == 2) ? U10f : (g == 3) ? U0o : U0u;
            Ut[idx] = U[h * HID + e];
        } else {
            U = (g == 0) ? U1i : (g == 1) ? U01f : (g == 2) ? U11f : (g == 3) ? U1o : U1u;
            Ut[idx] = U[h * HID + (e - 150)];
        }
    }
}

// Leaves: h = og*tanh(c), c = ig*uv.  Thread h computes all 3 gates for NBL leaves.
__global__ __launch_bounds__(192) void leaf_kernel(
    const float* __restrict__ Wt,
    const float* __restrict__ bi, const float* __restrict__ bo, const float* __restrict__ bu,
    const float* __restrict__ embt, const int* __restrict__ words,
    float* __restrict__ H, float* __restrict__ C)
{
    __shared__ __align__(16) float Xs[NBL][EMB];
    int tid = threadIdx.x;
    int leaf0 = LEAF_START + blockIdx.x * NBL;

    for (int m = 0; m < NBL; ++m) {
        int w = words[leaf0 + m];
        const float* src = embt + (long)w * EMB;
        for (int e = tid; e < EMB; e += 192) Xs[m][e] = src[e];
    }
    __syncthreads();

    int h = tid;
    if (h < HID) {
        float ai[NBL], ao[NBL], au[NBL];
#pragma unroll
        for (int m = 0; m < NBL; ++m) { ai[m] = 0.f; ao[m] = 0.f; au[m] = 0.f; }

        for (int e = 0; e < EMB; e += 4) {
            float wv[3][4];
#pragma unroll
            for (int q = 0; q < 4; ++q) {
                const float* p = Wt + (e + q) * 450 + h;
                wv[0][q] = p[0];
                wv[1][q] = p[150];
                wv[2][q] = p[300];
            }
#pragma unroll
            for (int m = 0; m < NBL; ++m) {
                float4 x = *(const float4*)&Xs[m][e];
                ai[m] += wv[0][0] * x.x + wv[0][1] * x.y + wv[0][2] * x.z + wv[0][3] * x.w;
                ao[m] += wv[1][0] * x.x + wv[1][1] * x.y + wv[1][2] * x.z + wv[1][3] * x.w;
                au[m] += wv[2][0] * x.x + wv[2][1] * x.y + wv[2][2] * x.z + wv[2][3] * x.w;
            }
        }

        float b_i = bi[h], b_o = bo[h], b_u = bu[h];
        for (int m = 0; m < NBL; ++m) {
            int node = leaf0 + m;
            float ig = sigmoidf_(ai[m] + b_i);
            float og = sigmoidf_(ao[m] + b_o);
            float uv = tanhf(au[m] + b_u);
            float c  = ig * uv;
            float hh = og * tanhf(c);
            H[(long)node * HID + h] = hh;
            C[(long)node * HID + h] = c;
        }
    }
}

// One internal level. x = lh||rh (300), 5 gates of 150 outputs each.
__global__ __launch_bounds__(192) void level_kernel(
    const float* __restrict__ Ut,
    const float* __restrict__ bbi, const float* __restrict__ bbf,
    const float* __restrict__ bbo, const float* __restrict__ bbu,
    const int* __restrict__ lchs, const int* __restrict__ rchs,
    float* __restrict__ H, float* __restrict__ C, int s, int count)
{
    __shared__ __align__(16) float Xs[NBI][2 * HID];
    __shared__ int lidx[NBI], ridx[NBI];
    int tid = threadIdx.x;
    int node0 = s + blockIdx.x * NBI;
    int nb = count - blockIdx.x * NBI; if (nb > NBI) nb = NBI;

    if (tid < nb) { lidx[tid] = lchs[node0 + tid]; ridx[tid] = rchs[node0 + tid]; }
    __syncthreads();

    for (int m = 0; m < NBI; ++m) {
        if (m < nb) {
            const float* hl = H + (long)lidx[m] * HID;
            const float* hr = H + (long)ridx[m] * HID;
            if (tid < HID) { Xs[m][tid] = hl[tid]; Xs[m][HID + tid] = hr[tid]; }
        } else {
            if (tid < HID) { Xs[m][tid] = 0.f; Xs[m][HID + tid] = 0.f; }
        }
    }
    __syncthreads();

    int h = tid;
    if (h < HID) {
        float acc[5][NBI];
#pragma unroll
        for (int g = 0; g < 5; ++g)
#pragma unroll
            for (int m = 0; m < NBI; ++m) acc[g][m] = 0.f;

        for (int e = 0; e < 2 * HID; e += 4) {
            float wv[5][4];
#pragma unroll
            for (int q = 0; q < 4; ++q) {
                const float* p = Ut + (e + q) * 750 + h;
#pragma unroll
                for (int g = 0; g < 5; ++g) wv[g][q] = p[g * 150];
            }
#pragma unroll
            for (int m = 0; m < NBI; ++m) {
                float4 x = *(const float4*)&Xs[m][e];
#pragma unroll
                for (int g = 0; g < 5; ++g)
                    acc[g][m] += wv[g][0] * x.x + wv[g][1] * x.y + wv[g][2] * x.z + wv[g][3] * x.w;
            }
        }

        float b_i = bbi[h], b_f = bbf[h], b_o = bbo[h], b_u = bbu[h];
        for (int m = 0; m < nb; ++m) {
            int node = node0 + m;
            float ig = sigmoidf_(acc[0][m] + b_i);
            float fl = sigmoidf_(acc[1][m] + b_f);
            float fr = sigmoidf_(acc[2][m] + b_f);
            float og = sigmoidf_(acc[3][m] + b_o);
            float uv = tanhf(acc[4][m] + b_u);
            float lc = C[(long)lidx[m] * HID + h];
            float rc = C[(long)ridx[m] * HID + h];
            float c  = ig * uv + fl * lc + fr * rc;
            float hh = og * tanhf(c);
            H[(long)node * HID + h] = hh;
            C[(long)node * HID + h] = c;
        }
    }
}

// loss_i = logsumexp(logits_i) - logits_i[score_i]; partial-sum per block.
__global__ __launch_bounds__(256) void loss_kernel(
    const float* __restrict__ H, const float* __restrict__ Why,
    const float* __restrict__ by, const int* __restrict__ scores,
    float* __restrict__ partials)
{
    __shared__ float Wys[NOUT * HID];
    __shared__ float bys[NOUT];
    __shared__ float red[256];
    int tid = threadIdx.x;
    for (int i = tid; i < NOUT * HID; i += 256) Wys[i] = Why[i];
    if (tid < NOUT) bys[tid] = by[tid];
    __syncthreads();

    float local = 0.f;
    for (int n = blockIdx.x * 256 + tid; n < NNODES; n += gridDim.x * 256) {
        const float* hr = H + (long)n * HID;
        float l0 = bys[0], l1 = bys[1], l2 = bys[2], l3 = bys[3], l4 = bys[4];
        for (int k = 0; k < HID; ++k) {
            float hv = hr[k];
            l0 += hv * Wys[0 * HID + k];
            l1 += hv * Wys[1 * HID + k];
            l2 += hv * Wys[2 * HID + k];
            l3 += hv * Wys[3 * HID + k];
            l4 += hv * Wys[4 * HID + k];
        }
        float mx = fmaxf(fmaxf(fmaxf(l0, l1), fmaxf(l2, l3)), l4);
        float se = __expf(l0 - mx) + __expf(l1 - mx) + __expf(l2 - mx) +
                   __expf(l3 - mx) + __expf(l4 - mx);
        float lse = mx + __logf(se);
        int sc = scores[n];
        float lsc = (sc == 0) ? l0 : (sc == 1) ? l1 : (sc == 2) ? l2 : (sc == 3) ? l3 : l4;
        local += lse - lsc;
    }
    red[tid] = local;
    __syncthreads();
    for (int st = 128; st > 0; st >>= 1) {
        if (tid < st) red[tid] += red[tid + st];
        __syncthreads();
    }
    if (tid == 0) partials[blockIdx.x] = red[0];
}

__global__ void loss_final(const float* __restrict__ partials, float* __restrict__ out, int nparts)
{
    if (threadIdx.x == 0 && blockIdx.x == 0) {
        float s = 0.f;
        for (int i = 0; i < nparts; ++i) s += partials[i];
        out[0] = s;
    }
}

extern "C" void kernel_launch(void* const* d_in, const int* in_sizes, int n_in,
                              void* d_out, int out_size, void* d_ws, size_t ws_size,
                              hipStream_t stream)
{
    const float* Wi   = (const float*)d_in[0];
    const float* bi   = (const float*)d_in[1];
    const float* Wo   = (const float*)d_in[2];
    const float* bo   = (const float*)d_in[3];
    const float* Wu   = (const float*)d_in[4];
    const float* bu   = (const float*)d_in[5];
    const float* U0i  = (const float*)d_in[6];
    const float* U1i  = (const float*)d_in[7];
    const float* bbi  = (const float*)d_in[8];
    const float* U00f = (const float*)d_in[9];
    const float* U01f = (const float*)d_in[10];
    const float* U10f = (const float*)d_in[11];
    const float* U11f = (const float*)d_in[12];
    const float* bbf  = (const float*)d_in[13];
    const float* U0o  = (const float*)d_in[14];
    const float* U1o  = (const float*)d_in[15];
    const float* bbo  = (const float*)d_in[16];
    const float* U0u  = (const float*)d_in[17];
    const float* U1u  = (const float*)d_in[18];
    const float* bbu  = (const float*)d_in[19];
    const float* Why  = (const float*)d_in[20];
    const float* by   = (const float*)d_in[21];
    const float* embt = (const float*)d_in[22];
    const int* scores = (const int*)d_in[23];
    const int* words  = (const int*)d_in[24];
    const int* lchs   = (const int*)d_in[25];
    const int* rchs   = (const int*)d_in[26];

    float* ws = (float*)d_ws;
    float* Wt = ws;                       // 300*450   = 135000
    float* Ut = Wt + 135000;              // 300*750   = 225000
    float* H  = Ut + 225000;              // 8191*150
    float* C  = H + (long)NNODES * HID;   // 8191*150
    float* partials = C + (long)NNODES * HID;  // LOSS_BLOCKS
    float* out = (float*)d_out;

    hipLaunchKernelGGL(prep_kernel, dim3(879), dim3(256), 0, stream,
                       Wi, Wo, Wu, U0i, U1i, U00f, U01f, U10f, U11f,
                       U0o, U1o, U0u, U1u, Wt, Ut);

    hipLaunchKernelGGL(leaf_kernel, dim3(NLEAF / NBL), dim3(192), 0, stream,
                       Wt, bi, bo, bu, embt, words, H, C);

    for (int d = 11; d >= 0; --d) {
        int s = (1 << d) - 1, count = 1 << d;
        int blocks = (count + NBI - 1) / NBI;
        hipLaunchKernelGGL(level_kernel, dim3(blocks), dim3(192), 0, stream,
                           Ut, bbi, bbf, bbo, bbu, lchs, rchs, H, C, s, count);
    }

    hipLaunchKernelGGL(loss_kernel, dim3(LOSS_BLOCKS), dim3(256), 0, stream,
                       H, Why, by, scores, partials);
    hipLaunchKernelGGL(loss_final, dim3(1), dim3(64), 0, stream,
                       partials, out, LOSS_BLOCKS);
}

// Round 2
// 527.589 us; speedup vs baseline: 1.5389x; 1.5389x over previous
//
#include <hip/hip_runtime.h>
#include <math.h>

#define HID 150
#define EMB 300
#define NOUT 5
#define NNODES 8191
#define NLEAF 4096
#define LEAF_START 4095
#define HSTR 152          // padded H/C row stride (608 B, 16B-aligned rows)
#define XSTR 20           // LDS x-tile stride (80 B rows, 16B-aligned)
#define UCOLS 752         // 750 gate-cols + 2 pad (3008 B rows)
#define WCOLS 452         // 450 leaf-cols + 2 pad (1808 B rows)

constexpr int LOSS_BLOCKS = 64;

__device__ __forceinline__ float sigmoidf_(float x) { return 1.0f / (1.0f + __expf(-x)); }

// ---------------- prep: transpose weights to e-major, zero-pad ----------------
// Wt2[e][j], j: 0..149 Wi | 150..299 Wo | 300..449 Wu | 450..451 zero
// Ut2[e][j], j: g*150+h, g: 0=i,1=fl,2=fr,3=o,4=u; e<150 left (U0*), e>=150 right (U1*); 750..751 zero
__global__ __launch_bounds__(256) void prep_kernel(
    const float* __restrict__ Wi, const float* __restrict__ Wo, const float* __restrict__ Wu,
    const float* __restrict__ U0i, const float* __restrict__ U1i,
    const float* __restrict__ U00f, const float* __restrict__ U01f,
    const float* __restrict__ U10f, const float* __restrict__ U11f,
    const float* __restrict__ U0o, const float* __restrict__ U1o,
    const float* __restrict__ U0u, const float* __restrict__ U1u,
    float* __restrict__ Wt2, float* __restrict__ Ut2)
{
    int idx = blockIdx.x * 256 + threadIdx.x;
    if (idx < EMB * WCOLS) {
        int e = idx / WCOLS, j = idx - e * WCOLS;
        float v = 0.f;
        if (j < 450) {
            const float* W; int h;
            if (j < 150)      { W = Wi; h = j; }
            else if (j < 300) { W = Wo; h = j - 150; }
            else              { W = Wu; h = j - 300; }
            v = W[h * EMB + e];
        }
        Wt2[idx] = v;
    }
    if (idx < EMB * UCOLS) {
        int e = idx / UCOLS, j = idx - e * UCOLS;
        float v = 0.f;
        if (j < 750) {
            int g = j / 150, h = j - g * 150;
            if (e < 150) {
                const float* U = (g == 0) ? U0i : (g == 1) ? U00f : (g == 2) ? U10f : (g == 3) ? U0o : U0u;
                v = U[h * HID + e];
            } else {
                const float* U = (g == 0) ? U1i : (g == 1) ? U01f : (g == 2) ? U11f : (g == 3) ? U1o : U1u;
                v = U[h * HID + (e - 150)];
            }
        }
        Ut2[idx] = v;
    }
}

// ---------------- leaf: NB=8 leaves/block, 128 threads ----------------
// x (emb rows) staged m-major in LDS; Wt2 streamed as coalesced float4;
// thread cg owns cols 4cg..4cg+3 for all 8 leaves (acc 8x4).
__global__ __launch_bounds__(128) void leaf_v2(
    const float* __restrict__ Wt2,
    const float* __restrict__ bi, const float* __restrict__ bo, const float* __restrict__ bu,
    const float* __restrict__ emb, const int* __restrict__ words,
    float* __restrict__ H, float* __restrict__ C)
{
    constexpr int NB = 8;
    __shared__ __align__(16) float Xs[EMB * XSTR];
    __shared__ __align__(16) float Gs[NB][WCOLS];
    const int tid = threadIdx.x;
    const int leaf0 = LEAF_START + blockIdx.x * NB;

    for (int m = 0; m < NB; ++m) {
        const float* src = emb + (long)words[leaf0 + m] * EMB;
        for (int e = tid; e < EMB; e += 128) Xs[e * XSTR + m] = src[e];
    }
    __syncthreads();

    if (tid < 113) {
        float acc[NB][4];
#pragma unroll
        for (int m = 0; m < NB; ++m)
#pragma unroll
            for (int q = 0; q < 4; ++q) acc[m][q] = 0.f;

        const float* wp = Wt2 + tid * 4;
#pragma unroll 4
        for (int k = 0; k < EMB; ++k) {
            float4 w = *(const float4*)(wp + (long)k * WCOLS);
            float x[NB];
#pragma unroll
            for (int m = 0; m < NB; ++m) x[m] = Xs[k * XSTR + m];
#pragma unroll
            for (int m = 0; m < NB; ++m) {
                acc[m][0] = fmaf(x[m], w.x, acc[m][0]);
                acc[m][1] = fmaf(x[m], w.y, acc[m][1]);
                acc[m][2] = fmaf(x[m], w.z, acc[m][2]);
                acc[m][3] = fmaf(x[m], w.w, acc[m][3]);
            }
        }
#pragma unroll
        for (int m = 0; m < NB; ++m)
            *(float4*)&Gs[m][tid * 4] = make_float4(acc[m][0], acc[m][1], acc[m][2], acc[m][3]);
    }
    __syncthreads();

    for (int p = tid; p < NB * HID; p += 128) {
        int m = p / HID, h = p - m * HID;
        float ig = sigmoidf_(Gs[m][h] + bi[h]);
        float og = sigmoidf_(Gs[m][150 + h] + bo[h]);
        float uv = tanhf(Gs[m][300 + h] + bu[h]);
        float c  = ig * uv;
        float hh = og * tanhf(c);
        long node = leaf0 + m;
        H[node * HSTR + h] = hh;
        C[node * HSTR + h] = c;
    }
}

// ---------------- internal level: NB nodes/block (template), 192 threads ----------------
template<int NB>
__global__ __launch_bounds__(192) void level_v2(
    const float* __restrict__ Ut2,
    const float* __restrict__ bbi, const float* __restrict__ bbf,
    const float* __restrict__ bbo, const float* __restrict__ bbu,
    const int* __restrict__ lchs, const int* __restrict__ rchs,
    float* __restrict__ H, float* __restrict__ C, int s, int count)
{
    __shared__ __align__(16) float Xs[EMB * XSTR];
    __shared__ __align__(16) float Gs[NB][UCOLS];
    __shared__ int lidx[NB], ridx[NB];
    const int tid = threadIdx.x;
    const int node0 = s + blockIdx.x * NB;
    int nb = count - blockIdx.x * NB; if (nb > NB) nb = NB;

    if (tid < NB) {
        int mm = tid < nb ? tid : 0;
        lidx[tid] = lchs[node0 + mm];
        ridx[tid] = rchs[node0 + mm];
    }
    __syncthreads();

    for (int m = 0; m < NB; ++m) {
        const float* hl = H + (long)lidx[m] * HSTR;
        const float* hr = H + (long)ridx[m] * HSTR;
        for (int e = tid; e < EMB; e += 192)
            Xs[e * XSTR + m] = (e < HID) ? hl[e] : hr[e - HID];
    }
    __syncthreads();

    if (tid < 188) {
        float acc[NB][4];
#pragma unroll
        for (int m = 0; m < NB; ++m)
#pragma unroll
            for (int q = 0; q < 4; ++q) acc[m][q] = 0.f;

        const float* wp = Ut2 + tid * 4;
#pragma unroll 4
        for (int k = 0; k < EMB; ++k) {
            float4 w = *(const float4*)(wp + (long)k * UCOLS);
            float x[NB];
#pragma unroll
            for (int m = 0; m < NB; ++m) x[m] = Xs[k * XSTR + m];
#pragma unroll
            for (int m = 0; m < NB; ++m) {
                acc[m][0] = fmaf(x[m], w.x, acc[m][0]);
                acc[m][1] = fmaf(x[m], w.y, acc[m][1]);
                acc[m][2] = fmaf(x[m], w.z, acc[m][2]);
                acc[m][3] = fmaf(x[m], w.w, acc[m][3]);
            }
        }
#pragma unroll
        for (int m = 0; m < NB; ++m)
            *(float4*)&Gs[m][tid * 4] = make_float4(acc[m][0], acc[m][1], acc[m][2], acc[m][3]);
    }
    __syncthreads();

    for (int p = tid; p < nb * HID; p += 192) {
        int m = p / HID, h = p - m * HID;
        float ig = sigmoidf_(Gs[m][h] + bbi[h]);
        float fl = sigmoidf_(Gs[m][150 + h] + bbf[h]);
        float fr = sigmoidf_(Gs[m][300 + h] + bbf[h]);
        float og = sigmoidf_(Gs[m][450 + h] + bbo[h]);
        float uv = tanhf(Gs[m][600 + h] + bbu[h]);
        float lc = C[(long)lidx[m] * HSTR + h];
        float rc = C[(long)ridx[m] * HSTR + h];
        float c  = ig * uv + fl * lc + fr * rc;
        float hh = og * tanhf(c);
        long node = node0 + m;
        H[node * HSTR + h] = hh;
        C[node * HSTR + h] = c;
    }
}

// ---------------- loss ----------------
__global__ __launch_bounds__(256) void loss_kernel(
    const float* __restrict__ H, const float* __restrict__ Why,
    const float* __restrict__ by, const int* __restrict__ scores,
    float* __restrict__ partials)
{
    __shared__ __align__(16) float Wys[NOUT][HSTR];
    __shared__ float bys[NOUT];
    __shared__ float red[256];
    int tid = threadIdx.x;
    for (int i = tid; i < NOUT * HID; i += 256) {
        int g = i / HID, k = i - g * HID;
        Wys[g][k] = Why[g * HID + k];
    }
    if (tid < NOUT) bys[tid] = by[tid];
    __syncthreads();

    float local = 0.f;
    for (int n = blockIdx.x * 256 + tid; n < NNODES; n += gridDim.x * 256) {
        const float* hr = H + (long)n * HSTR;
        float l0 = bys[0], l1 = bys[1], l2 = bys[2], l3 = bys[3], l4 = bys[4];
        for (int k = 0; k < 148; k += 4) {
            float4 hv = *(const float4*)(hr + k);
            float4 w0 = *(const float4*)&Wys[0][k];
            float4 w1 = *(const float4*)&Wys[1][k];
            float4 w2 = *(const float4*)&Wys[2][k];
            float4 w3 = *(const float4*)&Wys[3][k];
            float4 w4 = *(const float4*)&Wys[4][k];
            l0 += hv.x*w0.x + hv.y*w0.y + hv.z*w0.z + hv.w*w0.w;
            l1 += hv.x*w1.x + hv.y*w1.y + hv.z*w1.z + hv.w*w1.w;
            l2 += hv.x*w2.x + hv.y*w2.y + hv.z*w2.z + hv.w*w2.w;
            l3 += hv.x*w3.x + hv.y*w3.y + hv.z*w3.z + hv.w*w3.w;
            l4 += hv.x*w4.x + hv.y*w4.y + hv.z*w4.z + hv.w*w4.w;
        }
        for (int k = 148; k < HID; ++k) {
            float hv = hr[k];
            l0 += hv * Wys[0][k]; l1 += hv * Wys[1][k]; l2 += hv * Wys[2][k];
            l3 += hv * Wys[3][k]; l4 += hv * Wys[4][k];
        }
        float mx = fmaxf(fmaxf(fmaxf(l0, l1), fmaxf(l2, l3)), l4);
        float se = __expf(l0 - mx) + __expf(l1 - mx) + __expf(l2 - mx) +
                   __expf(l3 - mx) + __expf(l4 - mx);
        float lse = mx + __logf(se);
        int sc = scores[n];
        float lsc = (sc == 0) ? l0 : (sc == 1) ? l1 : (sc == 2) ? l2 : (sc == 3) ? l3 : l4;
        local += lse - lsc;
    }
    red[tid] = local;
    __syncthreads();
    for (int st = 128; st > 0; st >>= 1) {
        if (tid < st) red[tid] += red[tid + st];
        __syncthreads();
    }
    if (tid == 0) partials[blockIdx.x] = red[0];
}

__global__ void loss_final(const float* __restrict__ partials, float* __restrict__ out, int nparts)
{
    if (threadIdx.x == 0 && blockIdx.x == 0) {
        float s = 0.f;
        for (int i = 0; i < nparts; ++i) s += partials[i];
        out[0] = s;
    }
}

extern "C" void kernel_launch(void* const* d_in, const int* in_sizes, int n_in,
                              void* d_out, int out_size, void* d_ws, size_t ws_size,
                              hipStream_t stream)
{
    const float* Wi   = (const float*)d_in[0];
    const float* bi   = (const float*)d_in[1];
    const float* Wo   = (const float*)d_in[2];
    const float* bo   = (const float*)d_in[3];
    const float* Wu   = (const float*)d_in[4];
    const float* bu   = (const float*)d_in[5];
    const float* U0i  = (const float*)d_in[6];
    const float* U1i  = (const float*)d_in[7];
    const float* bbi  = (const float*)d_in[8];
    const float* U00f = (const float*)d_in[9];
    const float* U01f = (const float*)d_in[10];
    const float* U10f = (const float*)d_in[11];
    const float* U11f = (const float*)d_in[12];
    const float* bbf  = (const float*)d_in[13];
    const float* U0o  = (const float*)d_in[14];
    const float* U1o  = (const float*)d_in[15];
    const float* bbo  = (const float*)d_in[16];
    const float* U0u  = (const float*)d_in[17];
    const float* U1u  = (const float*)d_in[18];
    const float* bbu  = (const float*)d_in[19];
    const float* Why  = (const float*)d_in[20];
    const float* by   = (const float*)d_in[21];
    const float* emb  = (const float*)d_in[22];
    const int* scores = (const int*)d_in[23];
    const int* words  = (const int*)d_in[24];
    const int* lchs   = (const int*)d_in[25];
    const int* rchs   = (const int*)d_in[26];

    float* ws = (float*)d_ws;
    float* Wt2 = ws;                                  // 300*452 = 135600
    float* Ut2 = Wt2 + EMB * WCOLS;                   // 300*752 = 225600
    float* H   = Ut2 + EMB * UCOLS;                   // 8191*152
    float* C   = H + (long)NNODES * HSTR;             // 8191*152
    float* partials = C + (long)NNODES * HSTR;        // 64
    float* out = (float*)d_out;

    hipLaunchKernelGGL(prep_kernel, dim3(882), dim3(256), 0, stream,
                       Wi, Wo, Wu, U0i, U1i, U00f, U01f, U10f, U11f,
                       U0o, U1o, U0u, U1u, Wt2, Ut2);

    hipLaunchKernelGGL(leaf_v2, dim3(NLEAF / 8), dim3(128), 0, stream,
                       Wt2, bi, bo, bu, emb, words, H, C);

    for (int d = 11; d >= 0; --d) {
        int s = (1 << d) - 1, count = 1 << d;
        if (d == 11) {
            hipLaunchKernelGGL(HIP_KERNEL_NAME(level_v2<8>), dim3((count + 7) / 8), dim3(192), 0, stream,
                               Ut2, bbi, bbf, bbo, bbu, lchs, rchs, H, C, s, count);
        } else if (d >= 2) {
            hipLaunchKernelGGL(HIP_KERNEL_NAME(level_v2<4>), dim3((count + 3) / 4), dim3(192), 0, stream,
                               Ut2, bbi, bbf, bbo, bbu, lchs, rchs, H, C, s, count);
        } else if (d == 1) {
            hipLaunchKernelGGL(HIP_KERNEL_NAME(level_v2<2>), dim3(1), dim3(192), 0, stream,
                               Ut2, bbi, bbf, bbo, bbu, lchs, rchs, H, C, s, count);
        } else {
            hipLaunchKernelGGL(HIP_KERNEL_NAME(level_v2<1>), dim3(1), dim3(192), 0, stream,
                               Ut2, bbi, bbf, bbo, bbu, lchs, rchs, H, C, s, count);
        }
    }

    hipLaunchKernelGGL(loss_kernel, dim3(LOSS_BLOCKS), dim3(256), 0, stream,
                       H, Why, by, scores, partials);
    hipLaunchKernelGGL(loss_final, dim3(1), dim3(64), 0, stream,
                       partials, out, LOSS_BLOCKS);
}